// Round 7
// baseline (2827.227 us; speedup 1.0000x reference)
//
#include <hip/hip_runtime.h>
#include <hip/hip_fp16.h>

// BiLSTM-CRF forward, MI355X. Round 10: k_lstm v10 — dual-sequence interleave.
// v6/v8/v9 micro-edits were <=5%: the ~2900 stall cyc/step is DISTRIBUTED
// (poll limit-cycle + 400cyc serial tail + barrier skew), so hide ALL of it
// with independent work instead of attacking one term: each WG-pair now runs
// TWO (dir,b) sequences. wv[128] weights are shared (same dir); per superstep
// the two sequences' dot phases interleave, their polls soak ~2x longer, the
// two tails run on DISJOINT thread ranges (concurrent), and 2 barriers cover
// 2 timesteps. Grid 128 WGs = 2 dir x 32 batch-pairs x 2 col-halves.

typedef unsigned int  uint32;
typedef unsigned short ushort16;
typedef unsigned long long uint64;
typedef __attribute__((ext_vector_type(8))) short  short8;   // 8 bf16 (4 VGPRs) — MFMA A/B frag
typedef __attribute__((ext_vector_type(4))) float  floatx4;  // MFMA C/D frag
typedef __attribute__((ext_vector_type(2))) _Float16 half2t;

#define BB 64
#define TT 512
#define NT (BB*TT)        // 32768 rows
#define G4 1024           // 4*H
#define NL 9

__device__ inline float bf2f(ushort16 u) {
  return __builtin_bit_cast(float, ((uint32)u) << 16);
}
__device__ inline ushort16 f2bf(float f) {  // RN-even bf16
  uint32 u = __builtin_bit_cast(uint32, f);
  u += 0x7fffu + ((u >> 16) & 1u);
  return (ushort16)(u >> 16);
}
__device__ inline float sigf(float x)  { return 1.0f / (1.0f + __expf(-x)); }
__device__ inline float tanhf_(float x){ return 1.0f - 2.0f / (1.0f + __expf(2.0f * x)); }

__device__ inline float fdot2_(uint32 w, half2t h, float acc) {
  return __builtin_amdgcn_fdot2(__builtin_bit_cast(half2t, w), h, acc, false);
}

// LDS-only workgroup barrier: orders LDS ops, lets vmcnt free-run.
__device__ inline void bar_lds() {
  __builtin_amdgcn_sched_barrier(0);
  asm volatile("s_waitcnt lgkmcnt(0)" ::: "memory");
  __builtin_amdgcn_s_barrier();
  __builtin_amdgcn_sched_barrier(0);
}

// ---------------- K1: seq_len ----------------
__global__ __launch_bounds__(64) void k_seqlen(const int* __restrict__ tokens,
                                               int* __restrict__ slen,
                                               float* __restrict__ out_sl) {
  const int b = blockIdx.x, lane = threadIdx.x;
  int cnt = 0;
  for (int t = lane; t < TT; t += 64) cnt += (tokens[b * TT + t] != 0) ? 1 : 0;
  #pragma unroll
  for (int off = 32; off >= 1; off >>= 1) cnt += __shfl_down(cnt, off, 64);
  if (lane == 0) { slen[b] = cnt; out_sl[b] = (float)cnt; }
}

// ---------------- K2a: embedding gather -> bf16 A matrix [NT][256] ----------------
__global__ __launch_bounds__(256) void k_embed(const int* __restrict__ tokens,
                                               const float* __restrict__ emb,
                                               ushort16* __restrict__ A) {
  const int f = blockIdx.x * 256 + threadIdx.x;  // float4 group, NT*256/4 total
  const int e = f * 4;
  const int row = e >> 8;
  const int col = e & 255;
  const int tok = tokens[row];
  const float4 v = *(const float4*)(emb + (size_t)tok * 256 + col);
  uint32 lo = (uint32)f2bf(v.x) | ((uint32)f2bf(v.y) << 16);
  uint32 hi = (uint32)f2bf(v.z) | ((uint32)f2bf(v.w) << 16);
  *(uint2*)(A + e) = make_uint2(lo, hi);
}

// ---------------- K2b: BT[c][k] = Wx_{f|b}[k][c] bf16, c in [0,2048) ----------------
__global__ __launch_bounds__(256) void k_wxprep(const float* __restrict__ Wxf,
                                                const float* __restrict__ Wxb,
                                                ushort16* __restrict__ BT) {
  const int id = blockIdx.x * 256 + threadIdx.x;   // 2048*256
  const int c = id >> 8, k = id & 255;
  const float v = (c < G4) ? Wxf[k * G4 + c] : Wxb[k * G4 + (c - G4)];
  BT[c * 256 + k] = f2bf(v);
}

// ---------------- K2c: Wh -> half2 pack, layout [k2][1024] ----------------
__global__ __launch_bounds__(256) void k_whprep(const float* __restrict__ Wh,
                                                uint32* __restrict__ W2) {
  const int id = blockIdx.x * 256 + threadIdx.x;   // 128*1024
  const int k2 = id >> 10, c = id & 1023;
  const float w0 = Wh[(2 * k2) * G4 + c];
  const float w1 = Wh[(2 * k2 + 1) * G4 + c];
  const ushort16 b0 = __builtin_bit_cast(ushort16, (_Float16)w0);
  const ushort16 b1 = __builtin_bit_cast(ushort16, (_Float16)w1);
  W2[id] = ((uint32)b1 << 16) | (uint32)b0;
}

// ---------------- K3: xg GEMM  [NT,256] @ [256,2048] -> bf16 xg_f | xg_b ----------------
__global__ __launch_bounds__(256) void k_gemm_xg(const ushort16* __restrict__ A,
                                                 const ushort16* __restrict__ BT,
                                                 const float* __restrict__ bias_f,
                                                 const float* __restrict__ bias_b,
                                                 ushort16* __restrict__ xgf,
                                                 ushort16* __restrict__ xgb) {
  __shared__ __align__(16) ushort16 As[64 * 36];
  __shared__ __align__(16) ushort16 Bs[64 * 36];
  const int m0 = blockIdx.x * 64;
  const int n0 = blockIdx.y * 64;
  const int tid = threadIdx.x;
  const int wave = tid >> 6, lane = tid & 63;
  const int lr = tid >> 2;            // staging row 0..63
  const int lc = (tid & 3) * 8;       // staging col {0,8,16,24}
  const int am = lane & 15, aq = lane >> 4;
  floatx4 acc[4];
  #pragma unroll
  for (int j = 0; j < 4; ++j) acc[j] = (floatx4){0.f, 0.f, 0.f, 0.f};

  for (int k0 = 0; k0 < 256; k0 += 32) {
    const uint4 va = *(const uint4*)(A  + ((m0 + lr) * 256 + k0 + lc));
    const uint4 vb = *(const uint4*)(BT + ((n0 + lr) * 256 + k0 + lc));
    *(uint2*)&As[lr * 36 + lc]     = make_uint2(va.x, va.y);
    *(uint2*)&As[lr * 36 + lc + 4] = make_uint2(va.z, va.w);
    *(uint2*)&Bs[lr * 36 + lc]     = make_uint2(vb.x, vb.y);
    *(uint2*)&Bs[lr * 36 + lc + 4] = make_uint2(vb.z, vb.w);
    __syncthreads();
    union { uint2 u[2]; short8 s; } fa, fb;
    fa.u[0] = *(const uint2*)&As[(wave * 16 + am) * 36 + aq * 8];
    fa.u[1] = *(const uint2*)&As[(wave * 16 + am) * 36 + aq * 8 + 4];
    #pragma unroll
    for (int j = 0; j < 4; ++j) {
      fb.u[0] = *(const uint2*)&Bs[(j * 16 + am) * 36 + aq * 8];
      fb.u[1] = *(const uint2*)&Bs[(j * 16 + am) * 36 + aq * 8 + 4];
      acc[j] = __builtin_amdgcn_mfma_f32_16x16x32_bf16(fa.s, fb.s, acc[j], 0, 0, 0);
    }
    __syncthreads();
  }
  // C/D layout (m89/m91-verified): col = lane&15, row = (lane>>4)*4 + reg
  const int orow = m0 + wave * 16 + aq * 4;
  #pragma unroll
  for (int j = 0; j < 4; ++j) {
    const int col = n0 + j * 16 + am;
    const float bv = (col < G4) ? bias_f[col] : bias_b[col - G4];
    #pragma unroll
    for (int r = 0; r < 4; ++r) {
      const float v = acc[j][r] + bv;
      const int row = orow + r;
      if (col < G4) xgf[row * G4 + col] = f2bf(v);
      else          xgb[row * G4 + (col - G4)] = f2bf(v);
    }
  }
}

// ---------------- K3b: zero the h-exchange tag buffer (per launch/replay) ----------------
__global__ __launch_bounds__(256) void k_zero(uint64* __restrict__ xh) {
  xh[blockIdx.x * 256 + threadIdx.x] = 0ull;
}

// ---------------- K4: LSTM recurrence v10 — 2 seqs per WG-pair ----------------
// Grid 128: bid -> dir=bid>>6, pp=(bid>>1)&31, half=bid&1; partner = bid^1.
// Seqs: b0=pp, b1=pp+32. 512 threads; thread: q=tid>>7 (gate), r=tid&127,
// col=q*256+half*128+r. wv[128] own-half-first (shared by both seqs).
// h2[seq][0..63]=own pairs, [64..127]=peer pairs (single-buffered, bar-fenced).
// xh region per WG: [seq][par][64] u64 {tag=s+1, pair}. Every wave polls both
// seqs at step top; checks interleave with the other seq's dot phases.
// Tails run concurrently on disjoint thread ranges (tid<128 seq0, 128-255 seq1).
__global__ __launch_bounds__(512, 2) void k_lstm(const ushort16* __restrict__ xgf,
                                                 const ushort16* __restrict__ xgb,
                                                 const uint32* __restrict__ Whf,
                                                 const uint32* __restrict__ Whb,
                                                 uint64* __restrict__ xh,
                                                 float* __restrict__ enc) {
  __shared__ __align__(16) uint32 h2[2][128];   // [seq][slot] packed f16 pairs
  __shared__ float gl[2][512];                  // [seq][gatecol] transformed gates
  const int bid  = blockIdx.x;
  const int dir  = bid >> 6;
  const int pp   = (bid >> 1) & 31;
  const int half = bid & 1;
  const int b0   = pp, b1 = pp + 32;
  const int tid  = threadIdx.x;
  const int l = tid & 63;
  const int q = tid >> 7, r = tid & 127;
  const int col = q * 256 + half * 128 + r;
  const ushort16* __restrict__ xg = dir ? xgb : xgf;
  const uint32* __restrict__ W2   = dir ? Whb : Whf;
  uint64* const xmine = xh + ((size_t)bid << 8);          // [2 seq][2 par][64]
  const uint64* const xpeer = xh + ((size_t)(bid ^ 1) << 8);

  // Weight rows, permuted own-first; literal indices after unroll.
  const int ownBase  = half * 64;
  const int peerBase = 64 - ownBase;
  uint32 wv[128];
  #pragma unroll
  for (int i = 0; i < 64; ++i) wv[i]      = W2[(ownBase  + i) * 1024 + col];
  #pragma unroll
  for (int i = 0; i < 64; ++i) wv[64 + i] = W2[(peerBase + i) * 1024 + col];
  #pragma unroll
  for (int i = 0; i < 128; ++i) asm volatile("" : "+v"(wv[i]));

  if (tid < 256) h2[tid >> 7][tid & 127] = 0u;   // h0 = 0 both seqs
  float c_state = 0.f;                 // seq0 units in tid<128, seq1 in 128-255
  __syncthreads();

  const int t0 = dir ? (TT - 1) : 0;
  ushort16 xA0 = xg[(size_t)(b0 * TT + t0) * G4 + col];
  ushort16 xA1 = xg[(size_t)(b1 * TT + t0) * G4 + col];

#define HC(u) __builtin_bit_cast(half2t, u)
#define GR4(HB,B,A0,A1,A2,A3) { const uint4 hq = (HB)[B]; \
                 A0 = fdot2_(wv[(B)*4+0], HC(hq.x), A0); \
                 A1 = fdot2_(wv[(B)*4+1], HC(hq.y), A1); \
                 A2 = fdot2_(wv[(B)*4+2], HC(hq.z), A2); \
                 A3 = fdot2_(wv[(B)*4+3], HC(hq.w), A3); }
#define PH16(HB,S,A0,A1,A2,A3) \
  GR4(HB,(S)+0,A0,A1,A2,A3)  GR4(HB,(S)+1,A0,A1,A2,A3)  GR4(HB,(S)+2,A0,A1,A2,A3)  GR4(HB,(S)+3,A0,A1,A2,A3) \
  GR4(HB,(S)+4,A0,A1,A2,A3)  GR4(HB,(S)+5,A0,A1,A2,A3)  GR4(HB,(S)+6,A0,A1,A2,A3)  GR4(HB,(S)+7,A0,A1,A2,A3) \
  GR4(HB,(S)+8,A0,A1,A2,A3)  GR4(HB,(S)+9,A0,A1,A2,A3)  GR4(HB,(S)+10,A0,A1,A2,A3) GR4(HB,(S)+11,A0,A1,A2,A3) \
  GR4(HB,(S)+12,A0,A1,A2,A3) GR4(HB,(S)+13,A0,A1,A2,A3) GR4(HB,(S)+14,A0,A1,A2,A3) GR4(HB,(S)+15,A0,A1,A2,A3)

  for (int s = 0; s < TT; ++s) {
    const int par = s & 1;
    float a0 = bf2f(xA0), a1 = 0.f, a2 = 0.f, a3 = 0.f;  // seq0 accs
    float e0 = bf2f(xA1), e1 = 0.f, e2 = 0.f, e3 = 0.f;  // seq1 accs
    if (s + 1 < TT) {       // prefetch next step's x-gates (vmcnt free-runs)
      const int t1 = dir ? (TT - 2 - s) : (s + 1);
      xA0 = xg[(size_t)(b0 * TT + t1) * G4 + col];
      xA1 = xg[(size_t)(b1 * TT + t1) * G4 + col];
    }
    // ---- issue both peer polls EARLY: every wave, lane l -> word l ----
    const uint64* ppeer0 = xpeer +       (par << 6) + l;
    const uint64* ppeer1 = xpeer + 128 + (par << 6) + l;
    uint64 pv0 = 0, pv1 = 0;
    if (s > 0) {
      pv0 = __hip_atomic_load(ppeer0, __ATOMIC_RELAXED, __HIP_MEMORY_SCOPE_AGENT);
      pv1 = __hip_atomic_load(ppeer1, __ATOMIC_RELAXED, __HIP_MEMORY_SCOPE_AGENT);
    }
    __builtin_amdgcn_sched_barrier(0);
    const uint4* hb0 = (const uint4*)h2[0];
    const uint4* hb1 = (const uint4*)h2[1];
    // ---- seq0 phase A, then seq1 phase A (polls soak underneath) ----
    PH16(hb0, 0, a0, a1, a2, a3)
    PH16(hb1, 0, e0, e1, e2, e3)
    // ---- check seq0; redundant per-wave LDS write of peer half ----
    if (s > 0) {
      const uint32 want = (uint32)s;
      while (!__all((uint32)(pv0 >> 32) == want)) {
        __builtin_amdgcn_s_sleep(1);
        pv0 = __hip_atomic_load(ppeer0, __ATOMIC_RELAXED, __HIP_MEMORY_SCOPE_AGENT);
      }
      h2[0][64 + l] = (uint32)pv0;
    }
    __builtin_amdgcn_sched_barrier(0);
    asm volatile("s_waitcnt lgkmcnt(0)" ::: "memory");
    __builtin_amdgcn_sched_barrier(0);
    // ---- seq0 phase B + gl0 ----
    PH16(hb0, 16, a0, a1, a2, a3)
    {
      float tv = (a0 + a1) + (a2 + a3);
      tv = (q == 2) ? tanhf_(tv) : sigf(tv);
      gl[0][tid] = tv;
    }
    // ---- check seq1 ----
    if (s > 0) {
      const uint32 want = (uint32)s;
      while (!__all((uint32)(pv1 >> 32) == want)) {
        __builtin_amdgcn_s_sleep(1);
        pv1 = __hip_atomic_load(ppeer1, __ATOMIC_RELAXED, __HIP_MEMORY_SCOPE_AGENT);
      }
      h2[1][64 + l] = (uint32)pv1;
    }
    __builtin_amdgcn_sched_barrier(0);
    asm volatile("s_waitcnt lgkmcnt(0)" ::: "memory");
    __builtin_amdgcn_sched_barrier(0);
    // ---- seq1 phase B + gl1 ----
    PH16(hb1, 16, e0, e1, e2, e3)
    {
      float tv = (e0 + e1) + (e2 + e3);
      tv = (q == 2) ? tanhf_(tv) : sigf(tv);
      gl[1][tid] = tv;
    }
    bar_lds();
    // ---- dual tail: tid<128 -> seq0 unit tid; 128<=tid<256 -> seq1 ----
    if (tid < 256) {
      const int js = tid >> 7;
      const int u  = tid & 127;
      const float I = gl[js][u];
      const float F = gl[js][128 + u];
      const float G = gl[js][256 + u];
      const float O = gl[js][384 + u];
      c_state = F * c_state + I * G;
      const float h = O * tanhf_(c_state);
      const int hv = (int)(uint32)__builtin_bit_cast(ushort16, (_Float16)h);
      const int ho = __shfl_xor(hv, 1, 64);
      if (!(u & 1)) {
        const uint32 pk = ((uint32)hv & 0xffffu) | ((uint32)ho << 16);
        if (s + 1 < TT) {   // publish {tag=s+1, pair} for the peer WG
          const uint64 pv = ((uint64)(uint32)(s + 1) << 32) | (uint64)pk;
          __hip_atomic_store(xmine + (js << 7) + ((par ^ 1) << 6) + (u >> 1), pv,
                             __ATOMIC_RELAXED, __HIP_MEMORY_SCOPE_AGENT);
        }
        h2[js][u >> 1] = pk;              // own slots [0,64)
      }
      const int t = dir ? (TT - 1 - s) : s;
      const int b = js ? b1 : b0;
      enc[(size_t)(b * TT + t) * 512 + dir * 256 + half * 128 + u] = h;
    }
    bar_lds();
  }
#undef HC
#undef GR4
#undef PH16
}

// ---------------- K5: logits = enc @ W_dense + b ----------------
__global__ __launch_bounds__(256) void k_dense(const float* __restrict__ enc,
                                               const float* __restrict__ Wd,
                                               const float* __restrict__ bd,
                                               float* __restrict__ logits) {
  __shared__ float Wl[512 * NL];
  __shared__ float bl[NL];
  const int tid = threadIdx.x;
  for (int i = tid; i < 512 * NL; i += 256) Wl[i] = Wd[i];
  if (tid < NL) bl[tid] = bd[tid];
  __syncthreads();
  const int wave = tid >> 6, lane = tid & 63;
  const int row = blockIdx.x * 4 + wave;
  const float* er = enc + (size_t)row * 512;
  float p[NL];
  #pragma unroll
  for (int c = 0; c < NL; ++c) p[c] = 0.f;
  #pragma unroll
  for (int u = 0; u < 8; ++u) {
    const int k = u * 64 + lane;
    const float v = er[k];
    const float* wr = &Wl[k * NL];
    #pragma unroll
    for (int c = 0; c < NL; ++c) p[c] += v * wr[c];
  }
  #pragma unroll
  for (int c = 0; c < NL; ++c) {
    #pragma unroll
    for (int off = 32; off >= 1; off >>= 1) p[c] += __shfl_down(p[c], off, 64);
  }
  if (lane == 0) {
    float* orow = logits + (size_t)row * NL;
    #pragma unroll
    for (int c = 0; c < NL; ++c) orow[c] = p[c] + bl[c];
  }
}

// ---------------- K6: CRF log-likelihood ----------------
__global__ __launch_bounds__(64) void k_crf(const float* __restrict__ logits,
                                            const int* __restrict__ labels,
                                            const int* __restrict__ slen,
                                            const float* __restrict__ trans,
                                            float* __restrict__ out_ll) {
  __shared__ float tr[NL * NL];
  __shared__ float alpha[NL];
  const int b = blockIdx.x;
  const int lane = threadIdx.x;
  for (int i = lane; i < NL * NL; i += 64) tr[i] = trans[i];
  __syncthreads();
  const int len = slen[b];
  const int* tg = labels + b * TT;
  const float* lg = logits + (size_t)b * TT * NL;
  float s = 0.f;
  for (int t = lane; t < TT; t += 64)
    if (t < len) s += lg[t * NL + tg[t]];
  for (int t = lane; t < TT - 1; t += 64)
    if (t + 1 < len) s += tr[tg[t] * NL + tg[t + 1]];
  #pragma unroll
  for (int off = 32; off >= 1; off >>= 1) s += __shfl_down(s, off, 64);
  if (lane < NL) alpha[lane] = lg[lane];
  __syncthreads();
  if (lane < NL) {
    const int j = lane;
    for (int t = 1; t < TT; ++t) {
      if (t < len) {
        float av[NL];
        float m = -1e30f;
        #pragma unroll
        for (int i = 0; i < NL; ++i) { av[i] = alpha[i] + tr[i * NL + j]; m = fmaxf(m, av[i]); }
        float ss = 0.f;
        #pragma unroll
        for (int i = 0; i < NL; ++i) ss += __expf(av[i] - m);
        const float nj = m + __logf(ss) + lg[t * NL + j];
        alpha[j] = nj;
      }
    }
  }
  __syncthreads();
  if (lane == 0) {
    float m = -1e30f;
    #pragma unroll
    for (int i = 0; i < NL; ++i) m = fmaxf(m, alpha[i]);
    float ss = 0.f;
    #pragma unroll
    for (int i = 0; i < NL; ++i) ss += __expf(alpha[i] - m);
    out_ll[b] = s - (m + __logf(ss));
  }
}

extern "C" void kernel_launch(void* const* d_in, const int* in_sizes, int n_in,
                              void* d_out, int out_size, void* d_ws, size_t ws_size,
                              hipStream_t stream) {
  (void)in_sizes; (void)n_in; (void)out_size; (void)ws_size;
  const int*   tokens = (const int*)d_in[0];
  const int*   labels = (const int*)d_in[1];
  const float* emb    = (const float*)d_in[2];
  const float* Wxf    = (const float*)d_in[3];
  const float* Whf    = (const float*)d_in[4];
  const float* bf_    = (const float*)d_in[5];
  const float* Wxb    = (const float*)d_in[6];
  const float* Whb    = (const float*)d_in[7];
  const float* bb_    = (const float*)d_in[8];
  const float* Wd     = (const float*)d_in[9];
  const float* bd     = (const float*)d_in[10];
  const float* trans  = (const float*)d_in[11];
  float* out = (float*)d_out;   // [logits 294912][seq_len 64][ll 64]

  char* ws = (char*)d_ws;
  ushort16* A    = (ushort16*)(ws + 0);           // 16 MB  bf16 emb rows
  ushort16* BT   = (ushort16*)(ws + 16777216);    //  1 MB  Wx^T bf16 (2048x256)
  uint32*   W2f  = (uint32*)  (ws + 17825792);    // 512 KB Wh_f half2 [128][1024]
  uint32*   W2b  = (uint32*)  (ws + 18350080);    // 512 KB
  ushort16* xgf  = (ushort16*)(ws + 18874368);    // 64 MB  bf16 [NT][1024]
  ushort16* xgb  = (ushort16*)(ws + 85983232);    // 64 MB
  float*    enc  = (float*)   (ws + 153092096);   // 64 MB  fp32 [NT][512]
  int*      slen = (int*)     (ws + 220200960);   // 256 B
  // h-exchange buffer: 128 WG x 2 seq x 2 parity x 64 u64 = 32768 u64 = 256 KB.
  // Reuses the A region (dead after k_gemm_xg); k_zero resets tags before k_lstm.
  uint64*   xh   = (uint64*)  (ws + 0);

  k_seqlen<<<BB, 64, 0, stream>>>(tokens, slen, out + NT * NL);
  k_embed <<<NT * 256 / 4 / 256, 256, 0, stream>>>(tokens, emb, A);
  k_wxprep<<<2048 * 256 / 256, 256, 0, stream>>>(Wxf, Wxb, BT);
  k_whprep<<<128 * 1024 / 256, 256, 0, stream>>>(Whf, W2f);
  k_whprep<<<128 * 1024 / 256, 256, 0, stream>>>(Whb, W2b);
  k_gemm_xg<<<dim3(NT / 64, 2048 / 64), 256, 0, stream>>>(A, BT, bf_, bb_, xgf, xgb);
  k_zero  <<<128, 256, 0, stream>>>(xh);   // 32768 u64 tags -> 0 (per replay)
  k_lstm  <<<128, 512, 0, stream>>>(xgf, xgb, W2f, W2b, xh, enc);
  k_dense <<<NT / 4, 256, 0, stream>>>(enc, Wd, bd, out);
  k_crf   <<<BB, 64, 0, stream>>>(out, labels, slen, trans, out + NT * NL + BB);
}

// Round 8
// 1988.998 us; speedup vs baseline: 1.4214x; 1.4214x over previous
//
#include <hip/hip_runtime.h>
#include <hip/hip_fp16.h>

// BiLSTM-CRF forward, MI355X. Round 11: k_lstm v11 — single-WG-per-sequence,
// 1024 threads, NO cross-WG exchange. Lessons from v4-v10: the 2-WG split's
// LLC h-exchange stall (~2900 cyc/step) is not hidable (early-poll, vmcnt-free
// barriers, dual-seq interleave all failed); MFMA batching lengthens the
// serial chain. So remove the exchange: 16 waves/WG hold all 1024 gate
// columns with wv[128] register-resident (4 waves/SIMD x ~170 regs << 512
// budget -> no AGPR split, no accvgpr moves). Per step: 32 uniform b128 h
// reads + 128 fdot2/thread, gl, LDS-only barrier, 256-thread tail, barrier.

typedef unsigned int  uint32;
typedef unsigned short ushort16;
typedef unsigned long long uint64;
typedef __attribute__((ext_vector_type(8))) short  short8;   // 8 bf16 (4 VGPRs) — MFMA A/B frag
typedef __attribute__((ext_vector_type(4))) float  floatx4;  // MFMA C/D frag
typedef __attribute__((ext_vector_type(2))) _Float16 half2t;

#define BB 64
#define TT 512
#define NT (BB*TT)        // 32768 rows
#define G4 1024           // 4*H
#define NL 9

__device__ inline float bf2f(ushort16 u) {
  return __builtin_bit_cast(float, ((uint32)u) << 16);
}
__device__ inline ushort16 f2bf(float f) {  // RN-even bf16
  uint32 u = __builtin_bit_cast(uint32, f);
  u += 0x7fffu + ((u >> 16) & 1u);
  return (ushort16)(u >> 16);
}
__device__ inline float sigf(float x)  { return 1.0f / (1.0f + __expf(-x)); }
__device__ inline float tanhf_(float x){ return 1.0f - 2.0f / (1.0f + __expf(2.0f * x)); }

__device__ inline float fdot2_(uint32 w, half2t h, float acc) {
  return __builtin_amdgcn_fdot2(__builtin_bit_cast(half2t, w), h, acc, false);
}

// LDS-only workgroup barrier: orders LDS ops, lets vmcnt free-run
// (xg prefetch + enc stores never drain on the critical path).
__device__ inline void bar_lds() {
  __builtin_amdgcn_sched_barrier(0);
  asm volatile("s_waitcnt lgkmcnt(0)" ::: "memory");
  __builtin_amdgcn_s_barrier();
  __builtin_amdgcn_sched_barrier(0);
}

// ---------------- K1: seq_len ----------------
__global__ __launch_bounds__(64) void k_seqlen(const int* __restrict__ tokens,
                                               int* __restrict__ slen,
                                               float* __restrict__ out_sl) {
  const int b = blockIdx.x, lane = threadIdx.x;
  int cnt = 0;
  for (int t = lane; t < TT; t += 64) cnt += (tokens[b * TT + t] != 0) ? 1 : 0;
  #pragma unroll
  for (int off = 32; off >= 1; off >>= 1) cnt += __shfl_down(cnt, off, 64);
  if (lane == 0) { slen[b] = cnt; out_sl[b] = (float)cnt; }
}

// ---------------- K2a: embedding gather -> bf16 A matrix [NT][256] ----------------
__global__ __launch_bounds__(256) void k_embed(const int* __restrict__ tokens,
                                               const float* __restrict__ emb,
                                               ushort16* __restrict__ A) {
  const int f = blockIdx.x * 256 + threadIdx.x;  // float4 group, NT*256/4 total
  const int e = f * 4;
  const int row = e >> 8;
  const int col = e & 255;
  const int tok = tokens[row];
  const float4 v = *(const float4*)(emb + (size_t)tok * 256 + col);
  uint32 lo = (uint32)f2bf(v.x) | ((uint32)f2bf(v.y) << 16);
  uint32 hi = (uint32)f2bf(v.z) | ((uint32)f2bf(v.w) << 16);
  *(uint2*)(A + e) = make_uint2(lo, hi);
}

// ---------------- K2b: BT[c][k] = Wx_{f|b}[k][c] bf16, c in [0,2048) ----------------
__global__ __launch_bounds__(256) void k_wxprep(const float* __restrict__ Wxf,
                                                const float* __restrict__ Wxb,
                                                ushort16* __restrict__ BT) {
  const int id = blockIdx.x * 256 + threadIdx.x;   // 2048*256
  const int c = id >> 8, k = id & 255;
  const float v = (c < G4) ? Wxf[k * G4 + c] : Wxb[k * G4 + (c - G4)];
  BT[c * 256 + k] = f2bf(v);
}

// ---------------- K2c: Wh -> half2 pack, layout [k2][1024] ----------------
__global__ __launch_bounds__(256) void k_whprep(const float* __restrict__ Wh,
                                                uint32* __restrict__ W2) {
  const int id = blockIdx.x * 256 + threadIdx.x;   // 128*1024
  const int k2 = id >> 10, c = id & 1023;
  const float w0 = Wh[(2 * k2) * G4 + c];
  const float w1 = Wh[(2 * k2 + 1) * G4 + c];
  const ushort16 b0 = __builtin_bit_cast(ushort16, (_Float16)w0);
  const ushort16 b1 = __builtin_bit_cast(ushort16, (_Float16)w1);
  W2[id] = ((uint32)b1 << 16) | (uint32)b0;
}

// ---------------- K3: xg GEMM  [NT,256] @ [256,2048] -> bf16 xg_f | xg_b ----------------
__global__ __launch_bounds__(256) void k_gemm_xg(const ushort16* __restrict__ A,
                                                 const ushort16* __restrict__ BT,
                                                 const float* __restrict__ bias_f,
                                                 const float* __restrict__ bias_b,
                                                 ushort16* __restrict__ xgf,
                                                 ushort16* __restrict__ xgb) {
  __shared__ __align__(16) ushort16 As[64 * 36];
  __shared__ __align__(16) ushort16 Bs[64 * 36];
  const int m0 = blockIdx.x * 64;
  const int n0 = blockIdx.y * 64;
  const int tid = threadIdx.x;
  const int wave = tid >> 6, lane = tid & 63;
  const int lr = tid >> 2;            // staging row 0..63
  const int lc = (tid & 3) * 8;       // staging col {0,8,16,24}
  const int am = lane & 15, aq = lane >> 4;
  floatx4 acc[4];
  #pragma unroll
  for (int j = 0; j < 4; ++j) acc[j] = (floatx4){0.f, 0.f, 0.f, 0.f};

  for (int k0 = 0; k0 < 256; k0 += 32) {
    const uint4 va = *(const uint4*)(A  + ((m0 + lr) * 256 + k0 + lc));
    const uint4 vb = *(const uint4*)(BT + ((n0 + lr) * 256 + k0 + lc));
    *(uint2*)&As[lr * 36 + lc]     = make_uint2(va.x, va.y);
    *(uint2*)&As[lr * 36 + lc + 4] = make_uint2(va.z, va.w);
    *(uint2*)&Bs[lr * 36 + lc]     = make_uint2(vb.x, vb.y);
    *(uint2*)&Bs[lr * 36 + lc + 4] = make_uint2(vb.z, vb.w);
    __syncthreads();
    union { uint2 u[2]; short8 s; } fa, fb;
    fa.u[0] = *(const uint2*)&As[(wave * 16 + am) * 36 + aq * 8];
    fa.u[1] = *(const uint2*)&As[(wave * 16 + am) * 36 + aq * 8 + 4];
    #pragma unroll
    for (int j = 0; j < 4; ++j) {
      fb.u[0] = *(const uint2*)&Bs[(j * 16 + am) * 36 + aq * 8];
      fb.u[1] = *(const uint2*)&Bs[(j * 16 + am) * 36 + aq * 8 + 4];
      acc[j] = __builtin_amdgcn_mfma_f32_16x16x32_bf16(fa.s, fb.s, acc[j], 0, 0, 0);
    }
    __syncthreads();
  }
  // C/D layout (m89/m91-verified): col = lane&15, row = (lane>>4)*4 + reg
  const int orow = m0 + wave * 16 + aq * 4;
  #pragma unroll
  for (int j = 0; j < 4; ++j) {
    const int col = n0 + j * 16 + am;
    const float bv = (col < G4) ? bias_f[col] : bias_b[col - G4];
    #pragma unroll
    for (int r = 0; r < 4; ++r) {
      const float v = acc[j][r] + bv;
      const int row = orow + r;
      if (col < G4) xgf[row * G4 + col] = f2bf(v);
      else          xgb[row * G4 + (col - G4)] = f2bf(v);
    }
  }
}

// ---------------- K4: LSTM recurrence v11 — 1 WG/seq, 1024 threads ----------
// Grid 128: bid -> dir=bid>>6, b=bid&63. Thread tid owns gate column tid.
// wv[128] = W2 rows 0..127 at this column: register-resident, literal-indexed.
// h (256 f16 = 128 packed dwords) in LDS, parity double-buffered; read as 32
// wave-uniform b128 per step. Tail: tid<256 (unit u=tid) applies cell update,
// packs h pairs (even lanes write one dword). 2 LDS-only barriers/step.
__global__ __launch_bounds__(1024, 1) void k_lstm(const ushort16* __restrict__ xgf,
                                                  const ushort16* __restrict__ xgb,
                                                  const uint32* __restrict__ Whf,
                                                  const uint32* __restrict__ Whb,
                                                  float* __restrict__ enc) {
  __shared__ __align__(16) uint32 h2[2][128];   // packed f16 h pairs, dbuf by parity
  __shared__ float gl[1024];                    // transformed gate staging
  const int bid = blockIdx.x;
  const int dir = bid >> 6, b = bid & 63;
  const int tid = threadIdx.x;
  const int col = tid;                 // gate column 0..1023
  const int q = tid >> 8;              // gate index (0=i,1=f,2=g,3=o)
  const ushort16* __restrict__ xg = dir ? xgb : xgf;
  const uint32* __restrict__ W2   = dir ? Whb : Whf;

  // All 128 Wh k2-rows for this column: register-resident, pinned.
  uint32 wv[128];
  #pragma unroll
  for (int i = 0; i < 128; ++i) wv[i] = W2[i * 1024 + col];
  #pragma unroll
  for (int i = 0; i < 128; ++i) asm volatile("" : "+v"(wv[i]));

  if (tid < 128) h2[0][tid] = 0u;      // h0 = 0
  float c_state = 0.f;                 // live in tid<256 (unit u = tid)
  __syncthreads();

  const int t0 = dir ? (TT - 1) : 0;
  ushort16 xA = xg[(size_t)(b * TT + t0) * G4 + col];

#define HC(u) __builtin_bit_cast(half2t, u)
#define GR4(B) { const uint4 hq = hb[B]; \
                 a0 = fdot2_(wv[(B)*4+0], HC(hq.x), a0); \
                 a1 = fdot2_(wv[(B)*4+1], HC(hq.y), a1); \
                 a2 = fdot2_(wv[(B)*4+2], HC(hq.z), a2); \
                 a3 = fdot2_(wv[(B)*4+3], HC(hq.w), a3); }

  for (int s = 0; s < TT; ++s) {
    const int par = s & 1;
    float a0 = bf2f(xA), a1 = 0.f, a2 = 0.f, a3 = 0.f;
    if (s + 1 < TT) {       // prefetch next step's x-gate (vmcnt free-runs)
      const int t1 = dir ? (TT - 2 - s) : (s + 1);
      xA = xg[(size_t)(b * TT + t1) * G4 + col];
    }
    const uint4* hb = (const uint4*)h2[par];
    // full 256-dot: 32 uniform b128 reads, 128 fdot2 — all-literal indices
    GR4(0)  GR4(1)  GR4(2)  GR4(3)  GR4(4)  GR4(5)  GR4(6)  GR4(7)
    GR4(8)  GR4(9)  GR4(10) GR4(11) GR4(12) GR4(13) GR4(14) GR4(15)
    GR4(16) GR4(17) GR4(18) GR4(19) GR4(20) GR4(21) GR4(22) GR4(23)
    GR4(24) GR4(25) GR4(26) GR4(27) GR4(28) GR4(29) GR4(30) GR4(31)
    {
      float tv = (a0 + a1) + (a2 + a3);
      // gate nonlinearity in parallel across 1024 threads (q wave-uniform)
      tv = (q == 2) ? tanhf_(tv) : sigf(tv);
      gl[tid] = tv;
    }
    bar_lds();
    if (tid < 256) {   // tail: unit u = tid; c = F*c + I*G; h = O*tanh(c)
      const float I = gl[tid];
      const float F = gl[256 + tid];
      const float G = gl[512 + tid];
      const float O = gl[768 + tid];
      c_state = F * c_state + I * G;
      const float h = O * tanhf_(c_state);
      // pack f16 pairs; even lanes own one dword (pair index tid>>1)
      const int hv = (int)(uint32)__builtin_bit_cast(ushort16, (_Float16)h);
      const int ho = __shfl_xor(hv, 1, 64);
      if (!(tid & 1)) {
        const uint32 pk = ((uint32)hv & 0xffffu) | ((uint32)ho << 16);
        h2[par ^ 1][tid >> 1] = pk;
      }
      const int t = dir ? (TT - 1 - s) : s;
      enc[(size_t)(b * TT + t) * 512 + dir * 256 + tid] = h;
    }
    bar_lds();
  }
#undef HC
#undef GR4
}

// ---------------- K5: logits = enc @ W_dense + b ----------------
__global__ __launch_bounds__(256) void k_dense(const float* __restrict__ enc,
                                               const float* __restrict__ Wd,
                                               const float* __restrict__ bd,
                                               float* __restrict__ logits) {
  __shared__ float Wl[512 * NL];
  __shared__ float bl[NL];
  const int tid = threadIdx.x;
  for (int i = tid; i < 512 * NL; i += 256) Wl[i] = Wd[i];
  if (tid < NL) bl[tid] = bd[tid];
  __syncthreads();
  const int wave = tid >> 6, lane = tid & 63;
  const int row = blockIdx.x * 4 + wave;
  const float* er = enc + (size_t)row * 512;
  float p[NL];
  #pragma unroll
  for (int c = 0; c < NL; ++c) p[c] = 0.f;
  #pragma unroll
  for (int u = 0; u < 8; ++u) {
    const int k = u * 64 + lane;
    const float v = er[k];
    const float* wr = &Wl[k * NL];
    #pragma unroll
    for (int c = 0; c < NL; ++c) p[c] += v * wr[c];
  }
  #pragma unroll
  for (int c = 0; c < NL; ++c) {
    #pragma unroll
    for (int off = 32; off >= 1; off >>= 1) p[c] += __shfl_down(p[c], off, 64);
  }
  if (lane == 0) {
    float* orow = logits + (size_t)row * NL;
    #pragma unroll
    for (int c = 0; c < NL; ++c) orow[c] = p[c] + bl[c];
  }
}

// ---------------- K6: CRF log-likelihood ----------------
__global__ __launch_bounds__(64) void k_crf(const float* __restrict__ logits,
                                            const int* __restrict__ labels,
                                            const int* __restrict__ slen,
                                            const float* __restrict__ trans,
                                            float* __restrict__ out_ll) {
  __shared__ float tr[NL * NL];
  __shared__ float alpha[NL];
  const int b = blockIdx.x;
  const int lane = threadIdx.x;
  for (int i = lane; i < NL * NL; i += 64) tr[i] = trans[i];
  __syncthreads();
  const int len = slen[b];
  const int* tg = labels + b * TT;
  const float* lg = logits + (size_t)b * TT * NL;
  float s = 0.f;
  for (int t = lane; t < TT; t += 64)
    if (t < len) s += lg[t * NL + tg[t]];
  for (int t = lane; t < TT - 1; t += 64)
    if (t + 1 < len) s += tr[tg[t] * NL + tg[t + 1]];
  #pragma unroll
  for (int off = 32; off >= 1; off >>= 1) s += __shfl_down(s, off, 64);
  if (lane < NL) alpha[lane] = lg[lane];
  __syncthreads();
  if (lane < NL) {
    const int j = lane;
    for (int t = 1; t < TT; ++t) {
      if (t < len) {
        float av[NL];
        float m = -1e30f;
        #pragma unroll
        for (int i = 0; i < NL; ++i) { av[i] = alpha[i] + tr[i * NL + j]; m = fmaxf(m, av[i]); }
        float ss = 0.f;
        #pragma unroll
        for (int i = 0; i < NL; ++i) ss += __expf(av[i] - m);
        const float nj = m + __logf(ss) + lg[t * NL + j];
        alpha[j] = nj;
      }
    }
  }
  __syncthreads();
  if (lane == 0) {
    float m = -1e30f;
    #pragma unroll
    for (int i = 0; i < NL; ++i) m = fmaxf(m, alpha[i]);
    float ss = 0.f;
    #pragma unroll
    for (int i = 0; i < NL; ++i) ss += __expf(alpha[i] - m);
    out_ll[b] = s - (m + __logf(ss));
  }
}

extern "C" void kernel_launch(void* const* d_in, const int* in_sizes, int n_in,
                              void* d_out, int out_size, void* d_ws, size_t ws_size,
                              hipStream_t stream) {
  (void)in_sizes; (void)n_in; (void)out_size; (void)ws_size;
  const int*   tokens = (const int*)d_in[0];
  const int*   labels = (const int*)d_in[1];
  const float* emb    = (const float*)d_in[2];
  const float* Wxf    = (const float*)d_in[3];
  const float* Whf    = (const float*)d_in[4];
  const float* bf_    = (const float*)d_in[5];
  const float* Wxb    = (const float*)d_in[6];
  const float* Whb    = (const float*)d_in[7];
  const float* bb_    = (const float*)d_in[8];
  const float* Wd     = (const float*)d_in[9];
  const float* bd     = (const float*)d_in[10];
  const float* trans  = (const float*)d_in[11];
  float* out = (float*)d_out;   // [logits 294912][seq_len 64][ll 64]

  char* ws = (char*)d_ws;
  ushort16* A    = (ushort16*)(ws + 0);           // 16 MB  bf16 emb rows
  ushort16* BT   = (ushort16*)(ws + 16777216);    //  1 MB  Wx^T bf16 (2048x256)
  uint32*   W2f  = (uint32*)  (ws + 17825792);    // 512 KB Wh_f half2 [128][1024]
  uint32*   W2b  = (uint32*)  (ws + 18350080);    // 512 KB
  ushort16* xgf  = (ushort16*)(ws + 18874368);    // 64 MB  bf16 [NT][1024]
  ushort16* xgb  = (ushort16*)(ws + 85983232);    // 64 MB
  float*    enc  = (float*)   (ws + 153092096);   // 64 MB  fp32 [NT][512]
  int*      slen = (int*)     (ws + 220200960);   // 256 B

  k_seqlen<<<BB, 64, 0, stream>>>(tokens, slen, out + NT * NL);
  k_embed <<<NT * 256 / 4 / 256, 256, 0, stream>>>(tokens, emb, A);
  k_wxprep<<<2048 * 256 / 256, 256, 0, stream>>>(Wxf, Wxb, BT);
  k_whprep<<<128 * 1024 / 256, 256, 0, stream>>>(Whf, W2f);
  k_whprep<<<128 * 1024 / 256, 256, 0, stream>>>(Whb, W2b);
  k_gemm_xg<<<dim3(NT / 64, 2048 / 64), 256, 0, stream>>>(A, BT, bf_, bb_, xgf, xgb);
  k_lstm  <<<128, 1024, 0, stream>>>(xgf, xgb, W2f, W2b, enc);
  k_dense <<<NT / 4, 256, 0, stream>>>(enc, Wd, bd, out);
  k_crf   <<<BB, 64, 0, stream>>>(out, labels, slen, trans, out + NT * NL + BB);
}

// Round 9
// 1243.193 us; speedup vs baseline: 2.2742x; 1.5999x over previous
//
#include <hip/hip_runtime.h>
#include <hip/hip_fp16.h>

// BiLSTM-CRF forward, MI355X. Round 12: k_lstm v12 — k-split for 4 waves/SIMD.
// Lesson v11: 1024-thr WG caps regs at 128/thread (4 waves/SIMD forced);
// wv[128] designs are therefore stuck at 2 waves/SIMD with ~30% VALUBusy and
// ~3000 exposed stall cyc/step (common to ALL prior variants, exchange or not).
// v12 halves per-thread weights via k-split: 2 WGs/seq (v9 column split), 1024
// threads each. tid<512: own-half k-rows (64 dwords), compute immediately;
// tid>=512: peer-half k-rows, poll LLC tag then compute — poll RT overlapped
// by the own-k waves. Partials meet in LDS; transform on 512 threads; tail
// unchanged. 16 waves/CU on all 256 CUs.

typedef unsigned int  uint32;
typedef unsigned short ushort16;
typedef unsigned long long uint64;
typedef __attribute__((ext_vector_type(8))) short  short8;   // 8 bf16 (4 VGPRs) — MFMA A/B frag
typedef __attribute__((ext_vector_type(4))) float  floatx4;  // MFMA C/D frag
typedef __attribute__((ext_vector_type(2))) _Float16 half2t;

#define BB 64
#define TT 512
#define NT (BB*TT)        // 32768 rows
#define G4 1024           // 4*H
#define NL 9

__device__ inline float bf2f(ushort16 u) {
  return __builtin_bit_cast(float, ((uint32)u) << 16);
}
__device__ inline ushort16 f2bf(float f) {  // RN-even bf16
  uint32 u = __builtin_bit_cast(uint32, f);
  u += 0x7fffu + ((u >> 16) & 1u);
  return (ushort16)(u >> 16);
}
__device__ inline float sigf(float x)  { return 1.0f / (1.0f + __expf(-x)); }
__device__ inline float tanhf_(float x){ return 1.0f - 2.0f / (1.0f + __expf(2.0f * x)); }

__device__ inline float fdot2_(uint32 w, half2t h, float acc) {
  return __builtin_amdgcn_fdot2(__builtin_bit_cast(half2t, w), h, acc, false);
}

// LDS-only workgroup barrier: orders LDS ops, lets vmcnt free-run
// (xg prefetch / enc stores / LLC publishes never drain on the critical path).
__device__ inline void bar_lds() {
  __builtin_amdgcn_sched_barrier(0);
  asm volatile("s_waitcnt lgkmcnt(0)" ::: "memory");
  __builtin_amdgcn_s_barrier();
  __builtin_amdgcn_sched_barrier(0);
}

// ---------------- K1: seq_len ----------------
__global__ __launch_bounds__(64) void k_seqlen(const int* __restrict__ tokens,
                                               int* __restrict__ slen,
                                               float* __restrict__ out_sl) {
  const int b = blockIdx.x, lane = threadIdx.x;
  int cnt = 0;
  for (int t = lane; t < TT; t += 64) cnt += (tokens[b * TT + t] != 0) ? 1 : 0;
  #pragma unroll
  for (int off = 32; off >= 1; off >>= 1) cnt += __shfl_down(cnt, off, 64);
  if (lane == 0) { slen[b] = cnt; out_sl[b] = (float)cnt; }
}

// ---------------- K2a: embedding gather -> bf16 A matrix [NT][256] ----------------
__global__ __launch_bounds__(256) void k_embed(const int* __restrict__ tokens,
                                               const float* __restrict__ emb,
                                               ushort16* __restrict__ A) {
  const int f = blockIdx.x * 256 + threadIdx.x;  // float4 group, NT*256/4 total
  const int e = f * 4;
  const int row = e >> 8;
  const int col = e & 255;
  const int tok = tokens[row];
  const float4 v = *(const float4*)(emb + (size_t)tok * 256 + col);
  uint32 lo = (uint32)f2bf(v.x) | ((uint32)f2bf(v.y) << 16);
  uint32 hi = (uint32)f2bf(v.z) | ((uint32)f2bf(v.w) << 16);
  *(uint2*)(A + e) = make_uint2(lo, hi);
}

// ---------------- K2b: BT[c][k] = Wx_{f|b}[k][c] bf16, c in [0,2048) ----------------
__global__ __launch_bounds__(256) void k_wxprep(const float* __restrict__ Wxf,
                                                const float* __restrict__ Wxb,
                                                ushort16* __restrict__ BT) {
  const int id = blockIdx.x * 256 + threadIdx.x;   // 2048*256
  const int c = id >> 8, k = id & 255;
  const float v = (c < G4) ? Wxf[k * G4 + c] : Wxb[k * G4 + (c - G4)];
  BT[c * 256 + k] = f2bf(v);
}

// ---------------- K2c: Wh -> half2 pack, layout [k2][1024] ----------------
__global__ __launch_bounds__(256) void k_whprep(const float* __restrict__ Wh,
                                                uint32* __restrict__ W2) {
  const int id = blockIdx.x * 256 + threadIdx.x;   // 128*1024
  const int k2 = id >> 10, c = id & 1023;
  const float w0 = Wh[(2 * k2) * G4 + c];
  const float w1 = Wh[(2 * k2 + 1) * G4 + c];
  const ushort16 b0 = __builtin_bit_cast(ushort16, (_Float16)w0);
  const ushort16 b1 = __builtin_bit_cast(ushort16, (_Float16)w1);
  W2[id] = ((uint32)b1 << 16) | (uint32)b0;
}

// ---------------- K3: xg GEMM  [NT,256] @ [256,2048] -> bf16 xg_f | xg_b ----------------
__global__ __launch_bounds__(256) void k_gemm_xg(const ushort16* __restrict__ A,
                                                 const ushort16* __restrict__ BT,
                                                 const float* __restrict__ bias_f,
                                                 const float* __restrict__ bias_b,
                                                 ushort16* __restrict__ xgf,
                                                 ushort16* __restrict__ xgb) {
  __shared__ __align__(16) ushort16 As[64 * 36];
  __shared__ __align__(16) ushort16 Bs[64 * 36];
  const int m0 = blockIdx.x * 64;
  const int n0 = blockIdx.y * 64;
  const int tid = threadIdx.x;
  const int wave = tid >> 6, lane = tid & 63;
  const int lr = tid >> 2;            // staging row 0..63
  const int lc = (tid & 3) * 8;       // staging col {0,8,16,24}
  const int am = lane & 15, aq = lane >> 4;
  floatx4 acc[4];
  #pragma unroll
  for (int j = 0; j < 4; ++j) acc[j] = (floatx4){0.f, 0.f, 0.f, 0.f};

  for (int k0 = 0; k0 < 256; k0 += 32) {
    const uint4 va = *(const uint4*)(A  + ((m0 + lr) * 256 + k0 + lc));
    const uint4 vb = *(const uint4*)(BT + ((n0 + lr) * 256 + k0 + lc));
    *(uint2*)&As[lr * 36 + lc]     = make_uint2(va.x, va.y);
    *(uint2*)&As[lr * 36 + lc + 4] = make_uint2(va.z, va.w);
    *(uint2*)&Bs[lr * 36 + lc]     = make_uint2(vb.x, vb.y);
    *(uint2*)&Bs[lr * 36 + lc + 4] = make_uint2(vb.z, vb.w);
    __syncthreads();
    union { uint2 u[2]; short8 s; } fa, fb;
    fa.u[0] = *(const uint2*)&As[(wave * 16 + am) * 36 + aq * 8];
    fa.u[1] = *(const uint2*)&As[(wave * 16 + am) * 36 + aq * 8 + 4];
    #pragma unroll
    for (int j = 0; j < 4; ++j) {
      fb.u[0] = *(const uint2*)&Bs[(j * 16 + am) * 36 + aq * 8];
      fb.u[1] = *(const uint2*)&Bs[(j * 16 + am) * 36 + aq * 8 + 4];
      acc[j] = __builtin_amdgcn_mfma_f32_16x16x32_bf16(fa.s, fb.s, acc[j], 0, 0, 0);
    }
    __syncthreads();
  }
  // C/D layout (m89/m91-verified): col = lane&15, row = (lane>>4)*4 + reg
  const int orow = m0 + wave * 16 + aq * 4;
  #pragma unroll
  for (int j = 0; j < 4; ++j) {
    const int col = n0 + j * 16 + am;
    const float bv = (col < G4) ? bias_f[col] : bias_b[col - G4];
    #pragma unroll
    for (int r = 0; r < 4; ++r) {
      const float v = acc[j][r] + bv;
      const int row = orow + r;
      if (col < G4) xgf[row * G4 + col] = f2bf(v);
      else          xgb[row * G4 + (col - G4)] = f2bf(v);
    }
  }
}

// ---------------- K3b: zero the h-exchange tag buffer (per launch/replay) ----------------
__global__ __launch_bounds__(256) void k_zero(uint64* __restrict__ xh) {
  xh[blockIdx.x * 256 + threadIdx.x] = 0ull;
}

// ---------------- K4: LSTM recurrence v12 — 2 WGs/seq, 1024 thr, k-split ----
// Grid 256: bid -> dir=bid>>7, b=(bid>>1)&63, half=bid&1; partner = bid^1.
// 1024 threads. c512=tid&511 -> col = q*256 + half*128 + r (q=c512>>7,r=c512&127).
// tid<512  : wv[64] = W2 rows (half*64+i)     — OWN-half k  (compute at once)
// tid>=512 : wv[64] = W2 rows ((1-half)*64+i) — PEER-half k (poll, then compute)
// h2 LDS: slots [0,64) own pairs (tail-written), [64,128) peer (poll-written).
// Peer partials -> glp[512]; own-k threads combine+transform -> gl[512]; tail
// (tid<128) does cell update, packs h, publishes {tag=s+1,pair} u64 via LLC.
__global__ __launch_bounds__(1024, 1) void k_lstm(const ushort16* __restrict__ xgf,
                                                  const ushort16* __restrict__ xgb,
                                                  const uint32* __restrict__ Whf,
                                                  const uint32* __restrict__ Whb,
                                                  uint64* __restrict__ xh,
                                                  float* __restrict__ enc) {
  __shared__ __align__(16) uint32 h2[2][128];   // packed f16 h pairs, dbuf by parity
  __shared__ float gl[512];                     // transformed gates
  __shared__ float glp[512];                    // peer-k raw partials
  const int bid  = blockIdx.x;
  const int dir  = bid >> 7;
  const int b    = (bid >> 1) & 63;
  const int half = bid & 1;
  const int tid  = threadIdx.x;
  const int l    = tid & 63;
  const int c512 = tid & 511;
  const int q = c512 >> 7, r = c512 & 127;
  const int col = q * 256 + half * 128 + r;
  const bool ownk = (tid < 512);                // wave-uniform (waves 0-7 vs 8-15)
  const ushort16* __restrict__ xg = dir ? xgb : xgf;
  const uint32* __restrict__ W2   = dir ? Whb : Whf;
  uint64* const xmine = xh + ((size_t)bid << 7);          // [2 par][64] u64
  const uint64* const xpeer = xh + ((size_t)(bid ^ 1) << 7);

  // 64 weight rows for this thread's (col, k-half); literal-indexed after unroll.
  const int rowbase = ownk ? (half * 64) : (64 - half * 64);
  uint32 wv[64];
  #pragma unroll
  for (int i = 0; i < 64; ++i) wv[i] = W2[(rowbase + i) * 1024 + col];
  #pragma unroll
  for (int i = 0; i < 64; ++i) asm volatile("" : "+v"(wv[i]));

  if (tid < 128) h2[0][tid] = 0u;      // h0 = 0 (own + peer slots)
  float c_state = 0.f;                 // live in tid<128
  __syncthreads();

  ushort16 xA = (ushort16)0;
  if (ownk) {
    const int t0 = dir ? (TT - 1) : 0;
    xA = xg[(size_t)(b * TT + t0) * G4 + col];
  }

#define HC(u) __builtin_bit_cast(half2t, u)
#define GR4(B,W) { const uint4 hq = hb[B]; \
                 a0 = fdot2_(wv[(W)*4+0], HC(hq.x), a0); \
                 a1 = fdot2_(wv[(W)*4+1], HC(hq.y), a1); \
                 a2 = fdot2_(wv[(W)*4+2], HC(hq.z), a2); \
                 a3 = fdot2_(wv[(W)*4+3], HC(hq.w), a3); }

  for (int s = 0; s < TT; ++s) {
    const int par = s & 1;
    float a0 = 0.f, a1 = 0.f, a2 = 0.f, a3 = 0.f;
    const uint4* hb = (const uint4*)h2[par];
    if (ownk) {
      // ---- own-half dots (slots 0..15); overlaps the peer waves' poll ----
      a0 = bf2f(xA);
      if (s + 1 < TT) {       // prefetch next step's x-gate (vmcnt free-runs)
        const int t1 = dir ? (TT - 2 - s) : (s + 1);
        xA = xg[(size_t)(b * TT + t1) * G4 + col];
      }
      GR4(0,0)   GR4(1,1)   GR4(2,2)   GR4(3,3)
      GR4(4,4)   GR4(5,5)   GR4(6,6)   GR4(7,7)
      GR4(8,8)   GR4(9,9)   GR4(10,10) GR4(11,11)
      GR4(12,12) GR4(13,13) GR4(14,14) GR4(15,15)
    } else {
      // ---- poll peer h-half (waves 8-15, redundant per wave), then dots ----
      if (s > 0) {
        const uint64* pp = xpeer + (par << 6) + l;
        const uint32 want = (uint32)s;
        uint64 pv = __hip_atomic_load(pp, __ATOMIC_RELAXED, __HIP_MEMORY_SCOPE_AGENT);
        while (!__all((uint32)(pv >> 32) == want)) {
          __builtin_amdgcn_s_sleep(1);
          pv = __hip_atomic_load(pp, __ATOMIC_RELAXED, __HIP_MEMORY_SCOPE_AGENT);
        }
        h2[par][64 + l] = (uint32)pv;
        __builtin_amdgcn_sched_barrier(0);
        asm volatile("s_waitcnt lgkmcnt(0)" ::: "memory");   // own write visible
        __builtin_amdgcn_sched_barrier(0);
      }
      GR4(16,0)  GR4(17,1)  GR4(18,2)  GR4(19,3)
      GR4(20,4)  GR4(21,5)  GR4(22,6)  GR4(23,7)
      GR4(24,8)  GR4(25,9)  GR4(26,10) GR4(27,11)
      GR4(28,12) GR4(29,13) GR4(30,14) GR4(31,15)
      glp[c512] = (a0 + a1) + (a2 + a3);
    }
    bar_lds();
    if (ownk) {   // combine partials + gate nonlinearity (q wave-uniform)
      float v = ((a0 + a1) + (a2 + a3)) + glp[c512];
      v = (q == 2) ? tanhf_(v) : sigf(v);
      gl[c512] = v;
    }
    bar_lds();
    if (tid < 128) {   // tail: unit u = tid; c = F*c + I*G; h = O*tanh(c)
      const float I = gl[tid];
      const float F = gl[128 + tid];
      const float G = gl[256 + tid];
      const float O = gl[384 + tid];
      c_state = F * c_state + I * G;
      const float h = O * tanhf_(c_state);
      const int hv = (int)(uint32)__builtin_bit_cast(ushort16, (_Float16)h);
      const int ho = __shfl_xor(hv, 1, 64);
      if (!(tid & 1)) {
        const uint32 pk = ((uint32)hv & 0xffffu) | ((uint32)ho << 16);
        if (s + 1 < TT) {   // publish {tag=s+1, pair} for the peer WG — ASAP
          const uint64 pv = ((uint64)(uint32)(s + 1) << 32) | (uint64)pk;
          __hip_atomic_store(xmine + ((par ^ 1) << 6) + (tid >> 1), pv,
                             __ATOMIC_RELAXED, __HIP_MEMORY_SCOPE_AGENT);
        }
        h2[par ^ 1][tid >> 1] = pk;              // own slots [0,64)
      }
      const int t = dir ? (TT - 1 - s) : s;
      enc[(size_t)(b * TT + t) * 512 + dir * 256 + half * 128 + tid] = h;
    }
    bar_lds();
  }
#undef HC
#undef GR4
}

// ---------------- K5: logits = enc @ W_dense + b ----------------
__global__ __launch_bounds__(256) void k_dense(const float* __restrict__ enc,
                                               const float* __restrict__ Wd,
                                               const float* __restrict__ bd,
                                               float* __restrict__ logits) {
  __shared__ float Wl[512 * NL];
  __shared__ float bl[NL];
  const int tid = threadIdx.x;
  for (int i = tid; i < 512 * NL; i += 256) Wl[i] = Wd[i];
  if (tid < NL) bl[tid] = bd[tid];
  __syncthreads();
  const int wave = tid >> 6, lane = tid & 63;
  const int row = blockIdx.x * 4 + wave;
  const float* er = enc + (size_t)row * 512;
  float p[NL];
  #pragma unroll
  for (int c = 0; c < NL; ++c) p[c] = 0.f;
  #pragma unroll
  for (int u = 0; u < 8; ++u) {
    const int k = u * 64 + lane;
    const float v = er[k];
    const float* wr = &Wl[k * NL];
    #pragma unroll
    for (int c = 0; c < NL; ++c) p[c] += v * wr[c];
  }
  #pragma unroll
  for (int c = 0; c < NL; ++c) {
    #pragma unroll
    for (int off = 32; off >= 1; off >>= 1) p[c] += __shfl_down(p[c], off, 64);
  }
  if (lane == 0) {
    float* orow = logits + (size_t)row * NL;
    #pragma unroll
    for (int c = 0; c < NL; ++c) orow[c] = p[c] + bl[c];
  }
}

// ---------------- K6: CRF log-likelihood ----------------
__global__ __launch_bounds__(64) void k_crf(const float* __restrict__ logits,
                                            const int* __restrict__ labels,
                                            const int* __restrict__ slen,
                                            const float* __restrict__ trans,
                                            float* __restrict__ out_ll) {
  __shared__ float tr[NL * NL];
  __shared__ float alpha[NL];
  const int b = blockIdx.x;
  const int lane = threadIdx.x;
  for (int i = lane; i < NL * NL; i += 64) tr[i] = trans[i];
  __syncthreads();
  const int len = slen[b];
  const int* tg = labels + b * TT;
  const float* lg = logits + (size_t)b * TT * NL;
  float s = 0.f;
  for (int t = lane; t < TT; t += 64)
    if (t < len) s += lg[t * NL + tg[t]];
  for (int t = lane; t < TT - 1; t += 64)
    if (t + 1 < len) s += tr[tg[t] * NL + tg[t + 1]];
  #pragma unroll
  for (int off = 32; off >= 1; off >>= 1) s += __shfl_down(s, off, 64);
  if (lane < NL) alpha[lane] = lg[lane];
  __syncthreads();
  if (lane < NL) {
    const int j = lane;
    for (int t = 1; t < TT; ++t) {
      if (t < len) {
        float av[NL];
        float m = -1e30f;
        #pragma unroll
        for (int i = 0; i < NL; ++i) { av[i] = alpha[i] + tr[i * NL + j]; m = fmaxf(m, av[i]); }
        float ss = 0.f;
        #pragma unroll
        for (int i = 0; i < NL; ++i) ss += __expf(av[i] - m);
        const float nj = m + __logf(ss) + lg[t * NL + j];
        alpha[j] = nj;
      }
    }
  }
  __syncthreads();
  if (lane == 0) {
    float m = -1e30f;
    #pragma unroll
    for (int i = 0; i < NL; ++i) m = fmaxf(m, alpha[i]);
    float ss = 0.f;
    #pragma unroll
    for (int i = 0; i < NL; ++i) ss += __expf(alpha[i] - m);
    out_ll[b] = s - (m + __logf(ss));
  }
}

extern "C" void kernel_launch(void* const* d_in, const int* in_sizes, int n_in,
                              void* d_out, int out_size, void* d_ws, size_t ws_size,
                              hipStream_t stream) {
  (void)in_sizes; (void)n_in; (void)out_size; (void)ws_size;
  const int*   tokens = (const int*)d_in[0];
  const int*   labels = (const int*)d_in[1];
  const float* emb    = (const float*)d_in[2];
  const float* Wxf    = (const float*)d_in[3];
  const float* Whf    = (const float*)d_in[4];
  const float* bf_    = (const float*)d_in[5];
  const float* Wxb    = (const float*)d_in[6];
  const float* Whb    = (const float*)d_in[7];
  const float* bb_    = (const float*)d_in[8];
  const float* Wd     = (const float*)d_in[9];
  const float* bd     = (const float*)d_in[10];
  const float* trans  = (const float*)d_in[11];
  float* out = (float*)d_out;   // [logits 294912][seq_len 64][ll 64]

  char* ws = (char*)d_ws;
  ushort16* A    = (ushort16*)(ws + 0);           // 16 MB  bf16 emb rows
  ushort16* BT   = (ushort16*)(ws + 16777216);    //  1 MB  Wx^T bf16 (2048x256)
  uint32*   W2f  = (uint32*)  (ws + 17825792);    // 512 KB Wh_f half2 [128][1024]
  uint32*   W2b  = (uint32*)  (ws + 18350080);    // 512 KB
  ushort16* xgf  = (ushort16*)(ws + 18874368);    // 64 MB  bf16 [NT][1024]
  ushort16* xgb  = (ushort16*)(ws + 85983232);    // 64 MB
  float*    enc  = (float*)   (ws + 153092096);   // 64 MB  fp32 [NT][512]
  int*      slen = (int*)     (ws + 220200960);   // 256 B
  // h-exchange buffer: 256 WG x 2 parity x 64 u64 = 256 KB.
  // Reuses the A region (dead after k_gemm_xg); k_zero resets tags before k_lstm.
  uint64*   xh   = (uint64*)  (ws + 0);

  k_seqlen<<<BB, 64, 0, stream>>>(tokens, slen, out + NT * NL);
  k_embed <<<NT * 256 / 4 / 256, 256, 0, stream>>>(tokens, emb, A);
  k_wxprep<<<2048 * 256 / 256, 256, 0, stream>>>(Wxf, Wxb, BT);
  k_whprep<<<128 * 1024 / 256, 256, 0, stream>>>(Whf, W2f);
  k_whprep<<<128 * 1024 / 256, 256, 0, stream>>>(Whb, W2b);
  k_gemm_xg<<<dim3(NT / 64, 2048 / 64), 256, 0, stream>>>(A, BT, bf_, bb_, xgf, xgb);
  k_zero  <<<128, 256, 0, stream>>>(xh);   // 32768 u64 tags -> 0 (per replay)
  k_lstm  <<<256, 1024, 0, stream>>>(xgf, xgb, W2f, W2b, xh, enc);
  k_dense <<<NT / 4, 256, 0, stream>>>(enc, Wd, bd, out);
  k_crf   <<<BB, 64, 0, stream>>>(out, labels, slen, trans, out + NT * NL + BB);
}